// Round 3
// baseline (6327.111 us; speedup 1.0000x reference)
//
#include <hip/hip_runtime.h>
#include <cstdint>
#include <cstddef>

// Problem constants (from reference)
#define NN 50000
#define TT 8
#define FF 128
#define HH 128
#define EE 800000

__device__ __forceinline__ float sigmoidf(float x) { return 1.0f / (1.0f + expf(-x)); }

// ---------------- CSR build ----------------

__global__ void count_kernel(const int* __restrict__ dst, int E, int* __restrict__ counts) {
    for (int e = blockIdx.x * blockDim.x + threadIdx.x; e < E; e += gridDim.x * blockDim.x)
        atomicAdd(&counts[dst[e]], 1);
}

__global__ void dinv_kernel(const int* __restrict__ counts, float* __restrict__ dinv, int n) {
    int i = blockIdx.x * blockDim.x + threadIdx.x;
    if (i < n) dinv[i] = rsqrtf((float)(counts[i] + 1));
}

// single-block exclusive scan over counts[n] -> offsets[n+1]
__global__ void scan_kernel(const int* __restrict__ counts, int* __restrict__ offsets, int n) {
    __shared__ int sums[256];
    const int tid = threadIdx.x, T = blockDim.x;
    const int chunk = (n + T - 1) / T;
    const int b = tid * chunk, e = min(b + chunk, n);
    int s = 0;
    for (int i = b; i < e; ++i) s += counts[i];
    sums[tid] = s;
    __syncthreads();
    for (int o = 1; o < T; o <<= 1) {
        int v = 0;
        if (tid >= o) v = sums[tid - o];
        __syncthreads();
        if (tid >= o) sums[tid] += v;
        __syncthreads();
    }
    int pre = (tid == 0) ? 0 : sums[tid - 1];
    for (int i = b; i < e; ++i) { offsets[i] = pre; pre += counts[i]; }
    if (tid == T - 1) offsets[n] = pre;
}

__global__ void fill_kernel(const int* __restrict__ src, const int* __restrict__ dst, int E,
                            const int* __restrict__ offsets, int* __restrict__ cursor,
                            int* __restrict__ sorted) {
    for (int e = blockIdx.x * blockDim.x + threadIdx.x; e < E; e += gridDim.x * blockDim.x) {
        int d = dst[e];
        int pos = offsets[d] + atomicAdd(&cursor[d], 1);
        sorted[pos] = src[e];
    }
}

// ---------------- GCN GEMM: C[M,128] = (A[M,128] @ B[128,128]) * dinv[row] ----------------
// BM=64, BN=128, BK=32, 256 threads, 4x8 micro-tile.
__global__ __launch_bounds__(256) void gemm_gcn(const float* __restrict__ A,
                                                const float* __restrict__ B,
                                                const float* __restrict__ dinv,
                                                float* __restrict__ C, int M) {
    __shared__ float As[32][68];   // [k][m], padded
    __shared__ float Bs[32][128];  // [k][n]
    const int tid = threadIdx.x;
    const int tx = tid & 15;   // col group: cols tx*8..+7
    const int ty = tid >> 4;   // row group: rows ty*4..+3
    const int m0 = blockIdx.x * 64;
    float acc[4][8] = {};

    for (int kc = 0; kc < 128; kc += 32) {
        // A tile 64x32, transposed into LDS
        {
            int r = tid >> 3;
            int kq = (tid & 7) * 4;
#pragma unroll
            for (int p = 0; p < 2; ++p) {
                int row = r + p * 32;
                int gr = m0 + row;
                float4 v = {0, 0, 0, 0};
                if (gr < M) v = *(const float4*)&A[(size_t)gr * 128 + kc + kq];
                As[kq + 0][row] = v.x; As[kq + 1][row] = v.y;
                As[kq + 2][row] = v.z; As[kq + 3][row] = v.w;
            }
        }
        // B tile 32x128 direct
        {
            int kr = tid >> 5;
            int cq = (tid & 31) * 4;
#pragma unroll
            for (int p = 0; p < 4; ++p) {
                int row = kr + p * 8;
                *(float4*)&Bs[row][cq] = *(const float4*)&B[(size_t)(kc + row) * 128 + cq];
            }
        }
        __syncthreads();
#pragma unroll
        for (int kk = 0; kk < 32; ++kk) {
            const float4 a  = *(const float4*)&As[kk][ty * 4];
            const float4 bA = *(const float4*)&Bs[kk][tx * 8];
            const float4 bB = *(const float4*)&Bs[kk][tx * 8 + 4];
            const float av[4] = {a.x, a.y, a.z, a.w};
            const float bv[8] = {bA.x, bA.y, bA.z, bA.w, bB.x, bB.y, bB.z, bB.w};
#pragma unroll
            for (int i = 0; i < 4; ++i)
#pragma unroll
                for (int j = 0; j < 8; ++j) acc[i][j] = fmaf(av[i], bv[j], acc[i][j]);
        }
        __syncthreads();
    }
#pragma unroll
    for (int i = 0; i < 4; ++i) {
        int gr = m0 + ty * 4 + i;
        if (gr >= M) break;
        float d = dinv[gr];
        float4 o0 = {acc[i][0] * d, acc[i][1] * d, acc[i][2] * d, acc[i][3] * d};
        float4 o1 = {acc[i][4] * d, acc[i][5] * d, acc[i][6] * d, acc[i][7] * d};
        *(float4*)&C[(size_t)gr * 128 + tx * 8]     = o0;
        *(float4*)&C[(size_t)gr * 128 + tx * 8 + 4] = o1;
    }
}

// ---------------- aggregate: out[d] = relu(dinv[d]*(sum_{src in CSR[d]} hs[src] + hs[d]) + b) ----------------
// one wave (64 lanes) per node, 2 floats per lane
__global__ __launch_bounds__(256) void aggregate_kernel(const float* __restrict__ hs,
                                                        const int* __restrict__ offsets,
                                                        const int* __restrict__ sorted,
                                                        const float* __restrict__ dinv,
                                                        const float* __restrict__ bias,
                                                        float* __restrict__ out, int n) {
    const int lane = threadIdx.x & 63;
    const int wave = (blockIdx.x * blockDim.x + threadIdx.x) >> 6;
    const int nwaves = (gridDim.x * blockDim.x) >> 6;
    for (int d = wave; d < n; d += nwaves) {
        const int e0 = offsets[d], e1 = offsets[d + 1];
        float sx = 0.f, sy = 0.f;
        for (int e = e0; e < e1; e += 64) {
            const int cnt = min(64, e1 - e);
            int s = (lane < cnt) ? sorted[e + lane] : 0;
            for (int j = 0; j < cnt; ++j) {
                int sj = __shfl(s, j);
                float2 v = *(const float2*)&hs[(size_t)sj * 128 + lane * 2];
                sx += v.x; sy += v.y;
            }
        }
        float2 self = *(const float2*)&hs[(size_t)d * 128 + lane * 2];
        const float di = dinv[d];
        float ox = di * (sx + self.x) + bias[lane * 2];
        float oy = di * (sy + self.y) + bias[lane * 2 + 1];
        ox = fmaxf(ox, 0.f);
        oy = fmaxf(oy, 0.f);
        float2 o = {ox, oy};
        *(float2*)&out[(size_t)d * 128 + lane * 2] = o;
    }
}

// ---------------- fused LSTM step ----------------
// gates[32,512] = X@Wih^T + H@Whh^T + b per block (quadrant-looped), pointwise
// update in-register. No gates buffer in HBM. Each block reads h only for its
// OWN 32 rows and overwrites those same rows after the K-loop — no cross-block
// hazard.
__global__ __launch_bounds__(256) void lstm_fused(const float* __restrict__ X,
                                                  float* __restrict__ h,
                                                  float* __restrict__ c,
                                                  const float* __restrict__ Wih,
                                                  const float* __restrict__ Whh,
                                                  const float* __restrict__ bih,
                                                  const float* __restrict__ bhh,
                                                  int M) {
    __shared__ float As[32][36];   // [k][m] 32k x 32m, padded
    __shared__ float Bs[32][132];  // [k][j] 32k x 128j, padded
    const int tid = threadIdx.x;
    const int tx = tid & 15;
    const int ty = tid >> 4;
    const int m0 = blockIdx.x * 32;
    float acc[4][2][8] = {};  // [gate_quadrant][row][col]

#pragma unroll
    for (int s = 0; s < 2; ++s) {
        const float* A = s ? h : X;
        const float* W = s ? Whh : Wih;  // [512,128] row-major
        for (int kc = 0; kc < 128; kc += 32) {
            {
                int row = tid >> 3;
                int kq = (tid & 7) * 4;
                int gr = m0 + row;
                float4 v = {0, 0, 0, 0};
                if (gr < M) v = *(const float4*)&A[(size_t)gr * 128 + kc + kq];
                As[kq + 0][row] = v.x; As[kq + 1][row] = v.y;
                As[kq + 2][row] = v.z; As[kq + 3][row] = v.w;
            }
#pragma unroll
            for (int q = 0; q < 4; ++q) {
                {
                    int kq = (tid & 7) * 4;
#pragma unroll
                    for (int p = 0; p < 4; ++p) {
                        int j = (tid >> 3) + p * 32;
                        float4 v = *(const float4*)&W[(size_t)(q * 128 + j) * 128 + kc + kq];
                        Bs[kq + 0][j] = v.x; Bs[kq + 1][j] = v.y;
                        Bs[kq + 2][j] = v.z; Bs[kq + 3][j] = v.w;
                    }
                }
                __syncthreads();
#pragma unroll
                for (int kk = 0; kk < 32; ++kk) {
                    const float a0 = As[kk][ty * 2];
                    const float a1 = As[kk][ty * 2 + 1];
                    const float4 bA = *(const float4*)&Bs[kk][tx * 8];
                    const float4 bB = *(const float4*)&Bs[kk][tx * 8 + 4];
                    const float bv[8] = {bA.x, bA.y, bA.z, bA.w, bB.x, bB.y, bB.z, bB.w};
#pragma unroll
                    for (int j = 0; j < 8; ++j) {
                        acc[q][0][j] = fmaf(a0, bv[j], acc[q][0][j]);
                        acc[q][1][j] = fmaf(a1, bv[j], acc[q][1][j]);
                    }
                }
                __syncthreads();
            }
        }
    }

#pragma unroll
    for (int i = 0; i < 2; ++i) {
        const int gr = m0 + ty * 2 + i;
        if (gr >= M) continue;
#pragma unroll
        for (int j = 0; j < 8; ++j) {
            const int k = tx * 8 + j;
            const float gi = acc[0][i][j] + bih[k]       + bhh[k];
            const float gf = acc[1][i][j] + bih[128 + k] + bhh[128 + k];
            const float gg = acc[2][i][j] + bih[256 + k] + bhh[256 + k];
            const float go = acc[3][i][j] + bih[384 + k] + bhh[384 + k];
            const size_t idx = (size_t)gr * 128 + k;
            const float cn = sigmoidf(gf) * c[idx] + sigmoidf(gi) * tanhf(gg);
            const float hn = sigmoidf(go) * tanhf(cn);
            c[idx] = cn;
            h[idx] = hn;
        }
    }
}

// ---------------- launch ----------------
extern "C" void kernel_launch(void* const* d_in, const int* in_sizes, int n_in,
                              void* d_out, int out_size, void* d_ws, size_t ws_size,
                              hipStream_t stream) {
    const float* nf  = (const float*)d_in[0];  // [T,N,F]
    const int*   ei  = (const int*)d_in[1];    // [T,2,E]
    const float* W1  = (const float*)d_in[2];
    const float* b1  = (const float*)d_in[3];
    const float* W2  = (const float*)d_in[4];
    const float* b2  = (const float*)d_in[5];
    const float* Wih = (const float*)d_in[6];  // [512,128]
    const float* Whh = (const float*)d_in[7];
    const float* bih = (const float*)d_in[8];
    const float* bhh = (const float*)d_in[9];
    float* h = (float*)d_out;  // [N,128] — live LSTM hidden state

    // Workspace budget check FIRST: if d_ws is too small, launch nothing.
    // (d_out stays poisoned -> harness reports incorrect, not a dead container.)
    const size_t A = 256;  // alignment
    auto rnd = [&](size_t b) { return (b + A - 1) & ~(A - 1); };
    const size_t need = rnd((size_t)NN * 128 * 4)    // hs
                      + rnd((size_t)NN * 128 * 4)    // xbuf
                      + rnd((size_t)NN * 128 * 4)    // c
                      + rnd((size_t)EE * 4)          // sorted
                      + rnd((size_t)NN * 4)          // dinv
                      + rnd((size_t)NN * 4)          // counts
                      + rnd((size_t)NN * 4)          // cursor
                      + rnd((size_t)(NN + 1) * 4);   // offs
    if (ws_size < need) return;  // ~81 MB required

    char* ws = (char*)d_ws;
    size_t off = 0;
    auto alloc = [&](size_t bytes) -> void* {
        void* p = ws + off;
        off += rnd(bytes);
        return p;
    };
    float* hs     = (float*)alloc((size_t)NN * 128 * 4);
    float* xbuf   = (float*)alloc((size_t)NN * 128 * 4);
    float* c      = (float*)alloc((size_t)NN * 128 * 4);
    int*   sorted = (int*)alloc((size_t)EE * 4);
    float* dinv   = (float*)alloc((size_t)NN * 4);
    int*   counts = (int*)alloc((size_t)NN * 4);
    int*   cursor = (int*)alloc((size_t)NN * 4);
    int*   offs   = (int*)alloc((size_t)(NN + 1) * 4);

    hipMemsetAsync(h, 0, (size_t)NN * 128 * 4, stream);
    hipMemsetAsync(c, 0, (size_t)NN * 128 * 4, stream);

    const int gm64 = (NN + 63) / 64;  // 782
    const int gm32 = (NN + 31) / 32;  // 1563

    for (int t = 0; t < TT; ++t) {
        const float* x = nf + (size_t)t * NN * FF;
        const int* src = ei + (size_t)t * 2 * EE;
        const int* dst = src + EE;

        hipMemsetAsync(counts, 0, (size_t)NN * 4, stream);
        hipMemsetAsync(cursor, 0, (size_t)NN * 4, stream);
        count_kernel<<<1024, 256, 0, stream>>>(dst, EE, counts);
        dinv_kernel<<<(NN + 255) / 256, 256, 0, stream>>>(counts, dinv, NN);
        scan_kernel<<<1, 256, 0, stream>>>(counts, offs, NN);
        fill_kernel<<<1024, 256, 0, stream>>>(src, dst, EE, offs, cursor, sorted);

        // GCN layer 1: hs = (x@W1)*dinv ; xbuf = relu(agg + b1)
        gemm_gcn<<<gm64, 256, 0, stream>>>(x, W1, dinv, hs, NN);
        aggregate_kernel<<<(NN * 64) / 256, 256, 0, stream>>>(hs, offs, sorted, dinv, b1, xbuf, NN);
        // GCN layer 2: hs = (xbuf@W2)*dinv ; xbuf = relu(agg + b2) = emb
        gemm_gcn<<<gm64, 256, 0, stream>>>(xbuf, W2, dinv, hs, NN);
        aggregate_kernel<<<(NN * 64) / 256, 256, 0, stream>>>(hs, offs, sorted, dinv, b2, xbuf, NN);

        // LSTM step (fused gates GEMM + pointwise)
        lstm_fused<<<gm32, 256, 0, stream>>>(xbuf, h, c, Wih, Whh, bih, bhh, NN);
    }
}

// Round 4
// 3718.999 us; speedup vs baseline: 1.7013x; 1.7013x over previous
//
#include <hip/hip_runtime.h>
#include <cstdint>
#include <cstddef>

// Problem constants (from reference)
#define NN 50000
#define TT 8
#define FF 128
#define HH 128
#define EE 800000

typedef __attribute__((ext_vector_type(8))) short bf16x8;
typedef __attribute__((ext_vector_type(4))) float f32x4;
typedef unsigned int uint;
typedef unsigned short ushort;

__device__ __forceinline__ float sigmoidf(float x) { return 1.0f / (1.0f + expf(-x)); }

__device__ __forceinline__ ushort f2bf_rne(float x) {
    uint u = __float_as_uint(x);
    uint r = (u + 0x7FFFu + ((u >> 16) & 1u)) >> 16;
    return (ushort)r;
}
__device__ __forceinline__ float bf2f(ushort b) { return __uint_as_float(((uint)b) << 16); }
__device__ __forceinline__ void split1(float x, ushort& hi, ushort& lo) {
    ushort h = f2bf_rne(x);
    hi = h;
    lo = f2bf_rne(x - bf2f(h));
}

// ---------------- CSR build ----------------

__global__ void count_kernel(const int* __restrict__ dst, int E, int* __restrict__ counts) {
    for (int e = blockIdx.x * blockDim.x + threadIdx.x; e < E; e += gridDim.x * blockDim.x)
        atomicAdd(&counts[dst[e]], 1);
}

__global__ void dinv_kernel(const int* __restrict__ counts, float* __restrict__ dinv, int n) {
    int i = blockIdx.x * blockDim.x + threadIdx.x;
    if (i < n) dinv[i] = rsqrtf((float)(counts[i] + 1));
}

__global__ void scan_kernel(const int* __restrict__ counts, int* __restrict__ offsets, int n) {
    __shared__ int sums[256];
    const int tid = threadIdx.x, T = blockDim.x;
    const int chunk = (n + T - 1) / T;
    const int b = tid * chunk, e = min(b + chunk, n);
    int s = 0;
    for (int i = b; i < e; ++i) s += counts[i];
    sums[tid] = s;
    __syncthreads();
    for (int o = 1; o < T; o <<= 1) {
        int v = 0;
        if (tid >= o) v = sums[tid - o];
        __syncthreads();
        if (tid >= o) sums[tid] += v;
        __syncthreads();
    }
    int pre = (tid == 0) ? 0 : sums[tid - 1];
    for (int i = b; i < e; ++i) { offsets[i] = pre; pre += counts[i]; }
    if (tid == T - 1) offsets[n] = pre;
}

__global__ void fill_kernel(const int* __restrict__ src, const int* __restrict__ dst, int E,
                            const int* __restrict__ offsets, int* __restrict__ cursor,
                            int* __restrict__ sorted) {
    for (int e = blockIdx.x * blockDim.x + threadIdx.x; e < E; e += gridDim.x * blockDim.x) {
        int d = dst[e];
        int pos = offsets[d] + atomicAdd(&cursor[d], 1);
        sorted[pos] = src[e];
    }
}

// ---------------- weight prep ----------------
// GCN W [128k][128n] fp32 -> fragment-major bf16 hi/lo:
// out[((kc5*8 + q)*64 + lane)*8 + j] = W[kc5*32 + (lane>>4)*8 + j][q*16 + (lane&15)]
__global__ void prep_w_gcn(const float* __restrict__ W, ushort* __restrict__ oh,
                           ushort* __restrict__ ol) {
    const int bx = blockIdx.x;           // kc5*8 + q, 32 blocks
    const int kc5 = bx >> 3, q = bx & 7;
    const int l = threadIdx.x;           // 64
    const int n = q * 16 + (l & 15);
    const int kb = kc5 * 32 + (l >> 4) * 8;
    const size_t o = ((size_t)bx * 64 + l) * 8;
#pragma unroll
    for (int j = 0; j < 8; ++j) {
        float v = W[(size_t)(kb + j) * 128 + n];
        split1(v, oh[o + j], ol[o + j]);
    }
}

// LSTM W [512 srow][128 k] fp32, gate-permuted cols:
// col' = c15 + 16*q, q = 4*kk + g ; srow = g*128 + kk*16 + c15
// out[((kc5*32 + q)*64 + lane)*8 + j] = W[srow(q, lane&15)][kc5*32 + (lane>>4)*8 + j]
__global__ void prep_w_lstm(const float* __restrict__ W, ushort* __restrict__ oh,
                            ushort* __restrict__ ol) {
    const int bx = blockIdx.x;           // kc5*32 + q, 128 blocks
    const int kc5 = bx >> 5, q = bx & 31;
    const int l = threadIdx.x;           // 64
    const int c15 = l & 15;
    const int g = q & 3, kk = q >> 2;
    const int srow = g * 128 + kk * 16 + c15;
    const int kb = kc5 * 32 + (l >> 4) * 8;
    const size_t o = ((size_t)bx * 64 + l) * 8;
#pragma unroll
    for (int j = 0; j < 8; ++j) {
        float v = W[(size_t)srow * 128 + kb + j];
        split1(v, oh[o + j], ol[o + j]);
    }
}

// bcp[col'] = bih[srow] + bhh[srow]
__global__ void prep_bc(const float* __restrict__ bih, const float* __restrict__ bhh,
                        float* __restrict__ bcp) {
    const int cp = threadIdx.x;  // 512
    const int c15 = cp & 15, q = cp >> 4;
    const int g = q & 3, kk = q >> 2;
    const int srow = g * 128 + kk * 16 + c15;
    bcp[cp] = bih[srow] + bhh[srow];
}

// ---------------- GCN GEMM (MFMA bf16x3): C[M,128] = (A[M,128] @ W) * dinv[row] ----------------
// BM=64, BN=128, BK=32. 256 threads = 4 waves (2M x 2N). A via LDS hi/lo; B frags from global.
__global__ __launch_bounds__(256) void gemm_gcn_mfma(const float* __restrict__ A,
                                                     const ushort* __restrict__ Wfh,
                                                     const ushort* __restrict__ Wfl,
                                                     const float* __restrict__ dinv,
                                                     float* __restrict__ C, int M) {
    __shared__ ushort Ah[64][40];
    __shared__ ushort Al[64][40];
    const int tid = threadIdx.x;
    const int lane = tid & 63;
    const int w = tid >> 6;
    const int wm = w >> 1, wn = w & 1;
    const int l15 = lane & 15, l4 = lane >> 4;
    const int m0 = blockIdx.x * 64;

    f32x4 acc[2][4];
#pragma unroll
    for (int i = 0; i < 2; ++i)
#pragma unroll
        for (int j = 0; j < 4; ++j) acc[i][j] = (f32x4){0.f, 0.f, 0.f, 0.f};

    const int srow = tid >> 2;  // 0..63
    const int sseg = tid & 3;   // 0..3, 8 floats each
    const bool aval = (m0 + srow) < M;
    const float* aptr = A + (size_t)(m0 + srow) * 128 + sseg * 8;

    for (int kc5 = 0; kc5 < 4; ++kc5) {
        // stage A tile 64x32 -> hi/lo bf16
        float4 v0 = {0.f, 0.f, 0.f, 0.f}, v1 = {0.f, 0.f, 0.f, 0.f};
        if (aval) {
            v0 = *(const float4*)(aptr + kc5 * 32);
            v1 = *(const float4*)(aptr + kc5 * 32 + 4);
        }
        union { uint4 u; ushort s[8]; } ph, pl;
        split1(v0.x, ph.s[0], pl.s[0]); split1(v0.y, ph.s[1], pl.s[1]);
        split1(v0.z, ph.s[2], pl.s[2]); split1(v0.w, ph.s[3], pl.s[3]);
        split1(v1.x, ph.s[4], pl.s[4]); split1(v1.y, ph.s[5], pl.s[5]);
        split1(v1.z, ph.s[6], pl.s[6]); split1(v1.w, ph.s[7], pl.s[7]);
        *(uint4*)&Ah[srow][sseg * 8] = ph.u;
        *(uint4*)&Al[srow][sseg * 8] = pl.u;
        __syncthreads();

        // B fragments direct from global (fragment-major, coalesced 1KB/wave)
        bf16x8 bh[4], bl[4];
#pragma unroll
        for (int nf = 0; nf < 4; ++nf) {
            const size_t o = ((size_t)(kc5 * 8 + wn * 4 + nf) * 64 + lane) * 8;
            bh[nf] = *(const bf16x8*)(Wfh + o);
            bl[nf] = *(const bf16x8*)(Wfl + o);
        }
        bf16x8 ahf[2], alf[2];
#pragma unroll
        for (int mf = 0; mf < 2; ++mf) {
            ahf[mf] = *(const bf16x8*)&Ah[wm * 32 + mf * 16 + l15][l4 * 8];
            alf[mf] = *(const bf16x8*)&Al[wm * 32 + mf * 16 + l15][l4 * 8];
        }
#pragma unroll
        for (int mf = 0; mf < 2; ++mf)
#pragma unroll
            for (int nf = 0; nf < 4; ++nf) {
                acc[mf][nf] = __builtin_amdgcn_mfma_f32_16x16x32_bf16(ahf[mf], bh[nf], acc[mf][nf], 0, 0, 0);
                acc[mf][nf] = __builtin_amdgcn_mfma_f32_16x16x32_bf16(ahf[mf], bl[nf], acc[mf][nf], 0, 0, 0);
                acc[mf][nf] = __builtin_amdgcn_mfma_f32_16x16x32_bf16(alf[mf], bh[nf], acc[mf][nf], 0, 0, 0);
            }
        __syncthreads();
    }

#pragma unroll
    for (int mf = 0; mf < 2; ++mf)
#pragma unroll
        for (int r = 0; r < 4; ++r) {
            const int row = m0 + wm * 32 + mf * 16 + l4 * 4 + r;
            if (row < M) {
                const float d = dinv[row];
                float* cp = C + (size_t)row * 128 + wn * 64 + l15;
#pragma unroll
                for (int nf = 0; nf < 4; ++nf) cp[nf * 16] = acc[mf][nf][r] * d;
            }
        }
}

// ---------------- aggregate: out[d] = relu(dinv[d]*(sum_{src} hs[src] + hs[d]) + b) ----------------
__global__ __launch_bounds__(256) void aggregate_kernel(const float* __restrict__ hs,
                                                        const int* __restrict__ offsets,
                                                        const int* __restrict__ sorted,
                                                        const float* __restrict__ dinv,
                                                        const float* __restrict__ bias,
                                                        float* __restrict__ out, int n) {
    const int lane = threadIdx.x & 63;
    const int wave = (blockIdx.x * blockDim.x + threadIdx.x) >> 6;
    const int nwaves = (gridDim.x * blockDim.x) >> 6;
    for (int d = wave; d < n; d += nwaves) {
        const int e0 = offsets[d], e1 = offsets[d + 1];
        float sx = 0.f, sy = 0.f;
        for (int e = e0; e < e1; e += 64) {
            const int cnt = min(64, e1 - e);
            int s = (lane < cnt) ? sorted[e + lane] : 0;
            for (int j = 0; j < cnt; ++j) {
                int sj = __shfl(s, j);
                float2 v = *(const float2*)&hs[(size_t)sj * 128 + lane * 2];
                sx += v.x; sy += v.y;
            }
        }
        float2 self = *(const float2*)&hs[(size_t)d * 128 + lane * 2];
        const float di = dinv[d];
        float ox = di * (sx + self.x) + bias[lane * 2];
        float oy = di * (sy + self.y) + bias[lane * 2 + 1];
        ox = fmaxf(ox, 0.f);
        oy = fmaxf(oy, 0.f);
        float2 o = {ox, oy};
        *(float2*)&out[(size_t)d * 128 + lane * 2] = o;
    }
}

// ---------------- fused LSTM step (MFMA bf16x3, gate-permuted weights) ----------------
// gates[64,512] per block; BM=64, 512 threads = 8 waves (2M x 4N); pointwise in-lane.
__global__ __launch_bounds__(512) void lstm_mfma(const float* __restrict__ X,
                                                 float* __restrict__ h,
                                                 float* __restrict__ c,
                                                 const ushort* __restrict__ Wihfh,
                                                 const ushort* __restrict__ Wihfl,
                                                 const ushort* __restrict__ Whhfh,
                                                 const ushort* __restrict__ Whhfl,
                                                 const float* __restrict__ bcp, int M) {
    __shared__ ushort Ah[64][40];
    __shared__ ushort Al[64][40];
    const int tid = threadIdx.x;
    const int lane = tid & 63;
    const int w = tid >> 6;          // 0..7
    const int wm = w >> 2, wn = w & 3;
    const int l15 = lane & 15, l4 = lane >> 4;
    const int m0 = blockIdx.x * 64;

    f32x4 acc[2][8];
#pragma unroll
    for (int i = 0; i < 2; ++i)
#pragma unroll
        for (int j = 0; j < 8; ++j) acc[i][j] = (f32x4){0.f, 0.f, 0.f, 0.f};

    const int srow = tid >> 3;  // 0..63
    const int sseg = tid & 7;   // 0..7, 4 floats each
    const bool aval = (m0 + srow) < M;
    const size_t abase = (size_t)(m0 + srow) * 128 + sseg * 4;

    for (int half = 0; half < 2; ++half) {
        const float* Asrc = half ? h : X;
        const ushort* Bfh = half ? Whhfh : Wihfh;
        const ushort* Bfl = half ? Whhfl : Wihfl;
        for (int kc5 = 0; kc5 < 4; ++kc5) {
            float4 v = {0.f, 0.f, 0.f, 0.f};
            if (aval) v = *(const float4*)(Asrc + abase + kc5 * 32);
            union { uint2 u; ushort s[4]; } ph, pl;
            split1(v.x, ph.s[0], pl.s[0]); split1(v.y, ph.s[1], pl.s[1]);
            split1(v.z, ph.s[2], pl.s[2]); split1(v.w, ph.s[3], pl.s[3]);
            *(uint2*)&Ah[srow][sseg * 4] = ph.u;
            *(uint2*)&Al[srow][sseg * 4] = pl.u;
            __syncthreads();

            bf16x8 ahf[2], alf[2];
#pragma unroll
            for (int mf = 0; mf < 2; ++mf) {
                ahf[mf] = *(const bf16x8*)&Ah[wm * 32 + mf * 16 + l15][l4 * 8];
                alf[mf] = *(const bf16x8*)&Al[wm * 32 + mf * 16 + l15][l4 * 8];
            }
#pragma unroll
            for (int nf = 0; nf < 8; ++nf) {
                const size_t o = ((size_t)(kc5 * 32 + wn * 8 + nf) * 64 + lane) * 8;
                const bf16x8 bh = *(const bf16x8*)(Bfh + o);
                const bf16x8 bl = *(const bf16x8*)(Bfl + o);
#pragma unroll
                for (int mf = 0; mf < 2; ++mf) {
                    acc[mf][nf] = __builtin_amdgcn_mfma_f32_16x16x32_bf16(ahf[mf], bh, acc[mf][nf], 0, 0, 0);
                    acc[mf][nf] = __builtin_amdgcn_mfma_f32_16x16x32_bf16(ahf[mf], bl, acc[mf][nf], 0, 0, 0);
                    acc[mf][nf] = __builtin_amdgcn_mfma_f32_16x16x32_bf16(alf[mf], bh, acc[mf][nf], 0, 0, 0);
                }
            }
            __syncthreads();
        }
    }

    // epilogue: all 4 gates for feature k are lane-local (gate-permuted cols)
    float bb[8];
#pragma unroll
    for (int nf = 0; nf < 8; ++nf) bb[nf] = bcp[l15 + 16 * (wn * 8 + nf)];
#pragma unroll
    for (int mf = 0; mf < 2; ++mf)
#pragma unroll
        for (int r = 0; r < 4; ++r) {
            const int row = m0 + wm * 32 + mf * 16 + l4 * 4 + r;
            if (row >= M) continue;
#pragma unroll
            for (int kl = 0; kl < 2; ++kl) {
                const float gi = acc[mf][kl * 4 + 0][r] + bb[kl * 4 + 0];
                const float gf = acc[mf][kl * 4 + 1][r] + bb[kl * 4 + 1];
                const float gg = acc[mf][kl * 4 + 2][r] + bb[kl * 4 + 2];
                const float go = acc[mf][kl * 4 + 3][r] + bb[kl * 4 + 3];
                const int k = (2 * wn + kl) * 16 + l15;
                const size_t idx = (size_t)row * 128 + k;
                const float cn = sigmoidf(gf) * c[idx] + sigmoidf(gi) * tanhf(gg);
                const float hn = sigmoidf(go) * tanhf(cn);
                c[idx] = cn;
                h[idx] = hn;
            }
        }
}

// ---------------- launch ----------------
extern "C" void kernel_launch(void* const* d_in, const int* in_sizes, int n_in,
                              void* d_out, int out_size, void* d_ws, size_t ws_size,
                              hipStream_t stream) {
    const float* nf  = (const float*)d_in[0];  // [T,N,F]
    const int*   ei  = (const int*)d_in[1];    // [T,2,E]
    const float* W1  = (const float*)d_in[2];
    const float* b1  = (const float*)d_in[3];
    const float* W2  = (const float*)d_in[4];
    const float* b2  = (const float*)d_in[5];
    const float* Wih = (const float*)d_in[6];  // [512,128]
    const float* Whh = (const float*)d_in[7];
    const float* bih = (const float*)d_in[8];
    const float* bhh = (const float*)d_in[9];
    float* h = (float*)d_out;  // [N,128] — live LSTM hidden state

    const size_t AL = 256;
    auto rnd = [&](size_t b) { return (b + AL - 1) & ~(AL - 1); };
    const size_t sz_feat = (size_t)NN * 128 * 4;
    const size_t need = rnd(sz_feat) * 3                  // hs, xbuf, c
                      + rnd((size_t)EE * 4)               // sorted
                      + rnd((size_t)NN * 4) * 3           // dinv, counts, cursor
                      + rnd((size_t)(NN + 1) * 4)         // offs
                      + rnd((size_t)128 * 128 * 2) * 4    // GCN wf x4
                      + rnd((size_t)512 * 128 * 2) * 4    // LSTM wf x4
                      + rnd(512 * 4);                     // bcp
    if (ws_size < need) return;  // fail visibly (incorrect), not fatally

    char* ws = (char*)d_ws;
    size_t off = 0;
    auto alloc = [&](size_t bytes) -> void* {
        void* p = ws + off;
        off += rnd(bytes);
        return p;
    };
    float*  hs     = (float*)alloc(sz_feat);
    float*  xbuf   = (float*)alloc(sz_feat);
    float*  c      = (float*)alloc(sz_feat);
    int*    sorted = (int*)alloc((size_t)EE * 4);
    float*  dinv   = (float*)alloc((size_t)NN * 4);
    int*    counts = (int*)alloc((size_t)NN * 4);
    int*    cursor = (int*)alloc((size_t)NN * 4);
    int*    offs   = (int*)alloc((size_t)(NN + 1) * 4);
    ushort* wf1h   = (ushort*)alloc((size_t)128 * 128 * 2);
    ushort* wf1l   = (ushort*)alloc((size_t)128 * 128 * 2);
    ushort* wf2h   = (ushort*)alloc((size_t)128 * 128 * 2);
    ushort* wf2l   = (ushort*)alloc((size_t)128 * 128 * 2);
    ushort* wihfh  = (ushort*)alloc((size_t)512 * 128 * 2);
    ushort* wihfl  = (ushort*)alloc((size_t)512 * 128 * 2);
    ushort* whhfh  = (ushort*)alloc((size_t)512 * 128 * 2);
    ushort* whhfl  = (ushort*)alloc((size_t)512 * 128 * 2);
    float*  bcp    = (float*)alloc(512 * 4);

    hipMemsetAsync(h, 0, sz_feat, stream);
    hipMemsetAsync(c, 0, sz_feat, stream);

    // weight prep (runs every launch; trivial cost)
    prep_w_gcn<<<32, 64, 0, stream>>>(W1, wf1h, wf1l);
    prep_w_gcn<<<32, 64, 0, stream>>>(W2, wf2h, wf2l);
    prep_w_lstm<<<128, 64, 0, stream>>>(Wih, wihfh, wihfl);
    prep_w_lstm<<<128, 64, 0, stream>>>(Whh, whhfh, whhfl);
    prep_bc<<<1, 512, 0, stream>>>(bih, bhh, bcp);

    const int gm64 = (NN + 63) / 64;  // 782

    for (int t = 0; t < TT; ++t) {
        const float* x = nf + (size_t)t * NN * FF;
        const int* src = ei + (size_t)t * 2 * EE;
        const int* dst = src + EE;

        hipMemsetAsync(counts, 0, (size_t)NN * 4, stream);
        hipMemsetAsync(cursor, 0, (size_t)NN * 4, stream);
        count_kernel<<<1024, 256, 0, stream>>>(dst, EE, counts);
        dinv_kernel<<<(NN + 255) / 256, 256, 0, stream>>>(counts, dinv, NN);
        scan_kernel<<<1, 256, 0, stream>>>(counts, offs, NN);
        fill_kernel<<<1024, 256, 0, stream>>>(src, dst, EE, offs, cursor, sorted);

        // GCN layer 1
        gemm_gcn_mfma<<<gm64, 256, 0, stream>>>(x, wf1h, wf1l, dinv, hs, NN);
        aggregate_kernel<<<(NN * 64) / 256, 256, 0, stream>>>(hs, offs, sorted, dinv, b1, xbuf, NN);
        // GCN layer 2
        gemm_gcn_mfma<<<gm64, 256, 0, stream>>>(xbuf, wf2h, wf2l, dinv, hs, NN);
        aggregate_kernel<<<(NN * 64) / 256, 256, 0, stream>>>(hs, offs, sorted, dinv, b2, xbuf, NN);

        // fused LSTM step
        lstm_mfma<<<gm64, 512, 0, stream>>>(xbuf, h, c, wihfh, wihfl, whhfh, whhfl, bcp, NN);
    }
}

// Round 6
// 3209.315 us; speedup vs baseline: 1.9715x; 1.1588x over previous
//
#include <hip/hip_runtime.h>
#include <cstdint>
#include <cstddef>

// Problem constants (from reference)
#define NN 50000
#define TT 8
#define FF 128
#define HH 128
#define EE 800000

typedef __attribute__((ext_vector_type(8))) short bf16x8;
typedef __attribute__((ext_vector_type(4))) float f32x4;
typedef unsigned int uint;
typedef unsigned short ushort;

__device__ __forceinline__ float sigmoidf(float x) { return 1.0f / (1.0f + expf(-x)); }

__device__ __forceinline__ ushort f2bf_rne(float x) {
    uint u = __float_as_uint(x);
    uint r = (u + 0x7FFFu + ((u >> 16) & 1u)) >> 16;
    return (ushort)r;
}
__device__ __forceinline__ float bf2f(ushort b) { return __uint_as_float(((uint)b) << 16); }
__device__ __forceinline__ void split1(float x, ushort& hi, ushort& lo) {
    ushort h = f2bf_rne(x);
    hi = h;
    lo = f2bf_rne(x - bf2f(h));
}

// ---------------- batched CSR build (all 8 timesteps in one pass) ----------------

__global__ void count_all(const int* __restrict__ ei, int* __restrict__ counts) {
    const int t = blockIdx.y;
    const int* dst = ei + (size_t)t * 2 * EE + EE;
    for (int e = blockIdx.x * blockDim.x + threadIdx.x; e < EE; e += gridDim.x * blockDim.x)
        atomicAdd(&counts[t * NN + dst[e]], 1);
}

// 8 blocks, one per timestep; per-t exclusive scan of counts -> offs
__global__ void scan_all(const int* __restrict__ counts, int* __restrict__ offs) {
    __shared__ int sums[256];
    const int t = blockIdx.x;
    const int* cnt = counts + t * NN;
    int* off = offs + t * (NN + 1);
    const int tid = threadIdx.x, T = blockDim.x;
    const int chunk = (NN + T - 1) / T;
    const int b = tid * chunk, e = min(b + chunk, NN);
    int s = 0;
    for (int i = b; i < e; ++i) s += cnt[i];
    sums[tid] = s;
    __syncthreads();
    for (int o = 1; o < T; o <<= 1) {
        int v = 0;
        if (tid >= o) v = sums[tid - o];
        __syncthreads();
        if (tid >= o) sums[tid] += v;
        __syncthreads();
    }
    int pre = (tid == 0) ? 0 : sums[tid - 1];
    for (int i = b; i < e; ++i) { off[i] = pre; pre += cnt[i]; }
    if (tid == T - 1) off[NN] = pre;
}

// dinv from counts; cursor initialized to offsets (so fill produces absolute pos)
__global__ void init_aux(const int* __restrict__ counts, const int* __restrict__ offs,
                         float* __restrict__ dinv, int* __restrict__ cursor) {
    const int i = blockIdx.x * blockDim.x + threadIdx.x;
    if (i >= TT * NN) return;
    const int t = i / NN, idx = i - t * NN;
    dinv[i] = rsqrtf((float)(counts[i] + 1));
    cursor[i] = offs[t * (NN + 1) + idx];
}

__global__ void fill_all(const int* __restrict__ ei, int* __restrict__ cursor,
                         int* __restrict__ sorted) {
    const int t = blockIdx.y;
    const int* src = ei + (size_t)t * 2 * EE;
    const int* dst = src + EE;
    int* so = sorted + (size_t)t * EE;
    for (int e = blockIdx.x * blockDim.x + threadIdx.x; e < EE; e += gridDim.x * blockDim.x) {
        int d = dst[e];
        int pos = atomicAdd(&cursor[t * NN + d], 1);
        so[pos] = src[e];
    }
}

// ---------------- weight prep ----------------
// GCN W [128k][128n] fp32 -> fragment-major bf16 hi/lo:
// out[((kc5*8 + q)*64 + lane)*8 + j] = W[kc5*32 + (lane>>4)*8 + j][q*16 + (lane&15)]
__global__ void prep_w_gcn(const float* __restrict__ W, ushort* __restrict__ oh,
                           ushort* __restrict__ ol) {
    const int bx = blockIdx.x;           // kc5*8 + q, 32 blocks
    const int kc5 = bx >> 3, q = bx & 7;
    const int l = threadIdx.x;           // 64
    const int n = q * 16 + (l & 15);
    const int kb = kc5 * 32 + (l >> 4) * 8;
    const size_t o = ((size_t)bx * 64 + l) * 8;
#pragma unroll
    for (int j = 0; j < 8; ++j) {
        float v = W[(size_t)(kb + j) * 128 + n];
        split1(v, oh[o + j], ol[o + j]);
    }
}

// LSTM W [512 srow][128 k] fp32, gate-permuted cols:
// col' = c15 + 16*q, q = 4*kk + g ; srow = g*128 + kk*16 + c15
__global__ void prep_w_lstm(const float* __restrict__ W, ushort* __restrict__ oh,
                            ushort* __restrict__ ol) {
    const int bx = blockIdx.x;           // kc5*32 + q, 128 blocks
    const int kc5 = bx >> 5, q = bx & 31;
    const int l = threadIdx.x;           // 64
    const int c15 = l & 15;
    const int g = q & 3, kk = q >> 2;
    const int srow = g * 128 + kk * 16 + c15;
    const int kb = kc5 * 32 + (l >> 4) * 8;
    const size_t o = ((size_t)bx * 64 + l) * 8;
#pragma unroll
    for (int j = 0; j < 8; ++j) {
        float v = W[(size_t)srow * 128 + kb + j];
        split1(v, oh[o + j], ol[o + j]);
    }
}

__global__ void prep_bc(const float* __restrict__ bih, const float* __restrict__ bhh,
                        float* __restrict__ bcp) {
    const int cp = threadIdx.x;  // 512
    const int c15 = cp & 15, q = cp >> 4;
    const int g = q & 3, kk = q >> 2;
    const int srow = g * 128 + kk * 16 + c15;
    bcp[cp] = bih[srow] + bhh[srow];
}

// ---------------- GCN GEMM layer 1 (fp32 A via LDS split): hs = (A@W)*dinv ----------------
__global__ __launch_bounds__(256) void gemm_gcn_mfma(const float* __restrict__ A,
                                                     const ushort* __restrict__ Wfh,
                                                     const ushort* __restrict__ Wfl,
                                                     const float* __restrict__ dinv,
                                                     float* __restrict__ C, int M) {
    __shared__ ushort Ah[64][40];
    __shared__ ushort Al[64][40];
    const int tid = threadIdx.x;
    const int lane = tid & 63;
    const int w = tid >> 6;
    const int wm = w >> 1, wn = w & 1;
    const int l15 = lane & 15, l4 = lane >> 4;
    const int m0 = blockIdx.x * 64;

    f32x4 acc[2][4];
#pragma unroll
    for (int i = 0; i < 2; ++i)
#pragma unroll
        for (int j = 0; j < 4; ++j) acc[i][j] = (f32x4){0.f, 0.f, 0.f, 0.f};

    const int srow = tid >> 2;
    const int sseg = tid & 3;
    const bool aval = (m0 + srow) < M;
    const float* aptr = A + (size_t)(m0 + srow) * 128 + sseg * 8;

    for (int kc5 = 0; kc5 < 4; ++kc5) {
        float4 v0 = {0.f, 0.f, 0.f, 0.f}, v1 = {0.f, 0.f, 0.f, 0.f};
        if (aval) {
            v0 = *(const float4*)(aptr + kc5 * 32);
            v1 = *(const float4*)(aptr + kc5 * 32 + 4);
        }
        union { uint4 u; ushort s[8]; } ph, pl;
        split1(v0.x, ph.s[0], pl.s[0]); split1(v0.y, ph.s[1], pl.s[1]);
        split1(v0.z, ph.s[2], pl.s[2]); split1(v0.w, ph.s[3], pl.s[3]);
        split1(v1.x, ph.s[4], pl.s[4]); split1(v1.y, ph.s[5], pl.s[5]);
        split1(v1.z, ph.s[6], pl.s[6]); split1(v1.w, ph.s[7], pl.s[7]);
        *(uint4*)&Ah[srow][sseg * 8] = ph.u;
        *(uint4*)&Al[srow][sseg * 8] = pl.u;
        __syncthreads();

        bf16x8 bh[4], bl[4];
#pragma unroll
        for (int nf = 0; nf < 4; ++nf) {
            const size_t o = ((size_t)(kc5 * 8 + wn * 4 + nf) * 64 + lane) * 8;
            bh[nf] = *(const bf16x8*)(Wfh + o);
            bl[nf] = *(const bf16x8*)(Wfl + o);
        }
        bf16x8 ahf[2], alf[2];
#pragma unroll
        for (int mf = 0; mf < 2; ++mf) {
            ahf[mf] = *(const bf16x8*)&Ah[wm * 32 + mf * 16 + l15][l4 * 8];
            alf[mf] = *(const bf16x8*)&Al[wm * 32 + mf * 16 + l15][l4 * 8];
        }
#pragma unroll
        for (int mf = 0; mf < 2; ++mf)
#pragma unroll
            for (int nf = 0; nf < 4; ++nf) {
                acc[mf][nf] = __builtin_amdgcn_mfma_f32_16x16x32_bf16(ahf[mf], bh[nf], acc[mf][nf], 0, 0, 0);
                acc[mf][nf] = __builtin_amdgcn_mfma_f32_16x16x32_bf16(ahf[mf], bl[nf], acc[mf][nf], 0, 0, 0);
                acc[mf][nf] = __builtin_amdgcn_mfma_f32_16x16x32_bf16(alf[mf], bh[nf], acc[mf][nf], 0, 0, 0);
            }
        __syncthreads();
    }

#pragma unroll
    for (int mf = 0; mf < 2; ++mf)
#pragma unroll
        for (int r = 0; r < 4; ++r) {
            const int row = m0 + wm * 32 + mf * 16 + l4 * 4 + r;
            if (row < M) {
                const float d = dinv[row];
                float* cp = C + (size_t)row * 128 + wn * 64 + l15;
#pragma unroll
                for (int nf = 0; nf < 4; ++nf) cp[nf * 16] = acc[mf][nf][r] * d;
            }
        }
}

// ---------------- GCN GEMM layer 2 (A from bf16 hi/lo planes, no LDS/barriers) ----------------
__global__ __launch_bounds__(256) void gemm_frag(const ushort* __restrict__ Xh,
                                                 const ushort* __restrict__ Xl,
                                                 const ushort* __restrict__ Wfh,
                                                 const ushort* __restrict__ Wfl,
                                                 const float* __restrict__ dinv,
                                                 float* __restrict__ C, int M) {
    const int tid = threadIdx.x;
    const int lane = tid & 63;
    const int w = tid >> 6;
    const int wm = w >> 1, wn = w & 1;
    const int l15 = lane & 15, l4 = lane >> 4;
    const int m0 = blockIdx.x * 64;

    f32x4 acc[2][4];
#pragma unroll
    for (int i = 0; i < 2; ++i)
#pragma unroll
        for (int j = 0; j < 4; ++j) acc[i][j] = (f32x4){0.f, 0.f, 0.f, 0.f};

    size_t abase[2];
#pragma unroll
    for (int mf = 0; mf < 2; ++mf)
        abase[mf] = (size_t)(m0 + wm * 32 + mf * 16 + l15) * 128 + l4 * 8;

#pragma unroll
    for (int kc5 = 0; kc5 < 4; ++kc5) {
        bf16x8 ahf[2], alf[2];
#pragma unroll
        for (int mf = 0; mf < 2; ++mf) {
            ahf[mf] = *(const bf16x8*)(Xh + abase[mf] + kc5 * 32);
            alf[mf] = *(const bf16x8*)(Xl + abase[mf] + kc5 * 32);
        }
#pragma unroll
        for (int nf = 0; nf < 4; ++nf) {
            const size_t o = ((size_t)(kc5 * 8 + wn * 4 + nf) * 64 + lane) * 8;
            const bf16x8 bh = *(const bf16x8*)(Wfh + o);
            const bf16x8 bl = *(const bf16x8*)(Wfl + o);
#pragma unroll
            for (int mf = 0; mf < 2; ++mf) {
                acc[mf][nf] = __builtin_amdgcn_mfma_f32_16x16x32_bf16(ahf[mf], bh, acc[mf][nf], 0, 0, 0);
                acc[mf][nf] = __builtin_amdgcn_mfma_f32_16x16x32_bf16(ahf[mf], bl, acc[mf][nf], 0, 0, 0);
                acc[mf][nf] = __builtin_amdgcn_mfma_f32_16x16x32_bf16(alf[mf], bh, acc[mf][nf], 0, 0, 0);
            }
        }
    }

#pragma unroll
    for (int mf = 0; mf < 2; ++mf)
#pragma unroll
        for (int r = 0; r < 4; ++r) {
            const int row = m0 + wm * 32 + mf * 16 + l4 * 4 + r;
            if (row < M) {
                const float d = dinv[row];
                float* cp = C + (size_t)row * 128 + wn * 64 + l15;
#pragma unroll
                for (int nf = 0; nf < 4; ++nf) cp[nf * 16] = acc[mf][nf][r] * d;
            }
        }
}

// ---------------- aggregate: out = relu(dinv[d]*(sum_src hs[src] + hs[d]) + b) ----------------
// one wave per node; float4 per lane, 2 src rows per iteration; writes bf16 hi/lo planes
__global__ __launch_bounds__(256) void aggregate_f4(const float* __restrict__ hs,
                                                    const int* __restrict__ offsets,
                                                    const int* __restrict__ sorted,
                                                    const float* __restrict__ dinv,
                                                    const float* __restrict__ bias,
                                                    ushort* __restrict__ outh,
                                                    ushort* __restrict__ outl, int n) {
    const int lane = threadIdx.x & 63;
    const int half = lane >> 5, li = lane & 31;
    const int wave = (blockIdx.x * blockDim.x + threadIdx.x) >> 6;
    const int nwaves = (gridDim.x * blockDim.x) >> 6;
    for (int d = wave; d < n; d += nwaves) {
        const int e0 = offsets[d], e1 = offsets[d + 1];
        float sx = 0.f, sy = 0.f, sz = 0.f, sw = 0.f;
        for (int e = e0; e < e1; e += 64) {
            const int cnt = min(64, e1 - e);
            int s = (lane < cnt) ? sorted[e + lane] : 0;
            for (int j = 0; j < cnt; j += 2) {
                const int jj = j + half;
                const int r = __shfl(s, min(jj, cnt - 1));
                const float4 v = *(const float4*)&hs[(size_t)r * 128 + li * 4];
                if (jj < cnt) { sx += v.x; sy += v.y; sz += v.z; sw += v.w; }
            }
        }
        // cross-half reduce (each half summed a disjoint subset of srcs)
        sx += __shfl_xor(sx, 32);
        sy += __shfl_xor(sy, 32);
        sz += __shfl_xor(sz, 32);
        sw += __shfl_xor(sw, 32);

        const float4 self = *(const float4*)&hs[(size_t)d * 128 + li * 4];
        const float4 bb = *(const float4*)&bias[li * 4];
        const float di = dinv[d];
        float o0 = fmaxf(di * (sx + self.x) + bb.x, 0.f);
        float o1 = fmaxf(di * (sy + self.y) + bb.y, 0.f);
        float o2 = fmaxf(di * (sz + self.z) + bb.z, 0.f);
        float o3 = fmaxf(di * (sw + self.w) + bb.w, 0.f);

        ushort h0, l0, h1, l1, h2, l2, h3, l3;
        split1(o0, h0, l0); split1(o1, h1, l1); split1(o2, h2, l2); split1(o3, h3, l3);
        if (half == 0) {
            ushort4 ph = {h0, h1, h2, h3};
            *(ushort4*)&outh[(size_t)d * 128 + li * 4] = ph;
        } else {
            ushort4 pl = {l0, l1, l2, l3};
            *(ushort4*)&outl[(size_t)d * 128 + li * 4] = pl;
        }
    }
}

// ---------------- fused LSTM step (frag A loads, no LDS, no barriers) ----------------
// h planes ping-pong across t; fp32 h written to d_out; gate-permuted weights.
__global__ __launch_bounds__(512) void lstm_frag(const ushort* __restrict__ Xh,
                                                 const ushort* __restrict__ Xl,
                                                 const ushort* __restrict__ Hinh,
                                                 const ushort* __restrict__ Hinl,
                                                 ushort* __restrict__ Houth,
                                                 ushort* __restrict__ Houtl,
                                                 float* __restrict__ hout,
                                                 float* __restrict__ c,
                                                 const ushort* __restrict__ Wihfh,
                                                 const ushort* __restrict__ Wihfl,
                                                 const ushort* __restrict__ Whhfh,
                                                 const ushort* __restrict__ Whhfl,
                                                 const float* __restrict__ bcp, int M) {
    const int tid = threadIdx.x;
    const int lane = tid & 63;
    const int w = tid >> 6;          // 0..7
    const int wm = w >> 2, wn = w & 3;
    const int l15 = lane & 15, l4 = lane >> 4;
    const int m0 = blockIdx.x * 64;

    f32x4 acc[2][8];
#pragma unroll
    for (int i = 0; i < 2; ++i)
#pragma unroll
        for (int j = 0; j < 8; ++j) acc[i][j] = (f32x4){0.f, 0.f, 0.f, 0.f};

    size_t abase[2];
#pragma unroll
    for (int mf = 0; mf < 2; ++mf)
        abase[mf] = (size_t)(m0 + wm * 32 + mf * 16 + l15) * 128 + l4 * 8;

#pragma unroll
    for (int halfK = 0; halfK < 2; ++halfK) {
        const ushort* Ah = halfK ? Hinh : Xh;
        const ushort* Al = halfK ? Hinl : Xl;
        const ushort* Bfh = halfK ? Whhfh : Wihfh;
        const ushort* Bfl = halfK ? Whhfl : Wihfl;
#pragma unroll
        for (int kc5 = 0; kc5 < 4; ++kc5) {
            bf16x8 ahf[2], alf[2];
#pragma unroll
            for (int mf = 0; mf < 2; ++mf) {
                ahf[mf] = *(const bf16x8*)(Ah + abase[mf] + kc5 * 32);
                alf[mf] = *(const bf16x8*)(Al + abase[mf] + kc5 * 32);
            }
#pragma unroll
            for (int nf = 0; nf < 8; ++nf) {
                const size_t o = ((size_t)(kc5 * 32 + wn * 8 + nf) * 64 + lane) * 8;
                const bf16x8 bh = *(const bf16x8*)(Bfh + o);
                const bf16x8 bl = *(const bf16x8*)(Bfl + o);
#pragma unroll
                for (int mf = 0; mf < 2; ++mf) {
                    acc[mf][nf] = __builtin_amdgcn_mfma_f32_16x16x32_bf16(ahf[mf], bh, acc[mf][nf], 0, 0, 0);
                    acc[mf][nf] = __builtin_amdgcn_mfma_f32_16x16x32_bf16(ahf[mf], bl, acc[mf][nf], 0, 0, 0);
                    acc[mf][nf] = __builtin_amdgcn_mfma_f32_16x16x32_bf16(alf[mf], bh, acc[mf][nf], 0, 0, 0);
                }
            }
        }
    }

    // epilogue: all 4 gates for feature k lane-local (gate-permuted weight cols)
    float bb[8];
#pragma unroll
    for (int nf = 0; nf < 8; ++nf) bb[nf] = bcp[l15 + 16 * (wn * 8 + nf)];
#pragma unroll
    for (int mf = 0; mf < 2; ++mf)
#pragma unroll
        for (int r = 0; r < 4; ++r) {
            const int row = m0 + wm * 32 + mf * 16 + l4 * 4 + r;
            if (row >= M) continue;
#pragma unroll
            for (int kl = 0; kl < 2; ++kl) {
                const float gi = acc[mf][kl * 4 + 0][r] + bb[kl * 4 + 0];
                const float gf = acc[mf][kl * 4 + 1][r] + bb[kl * 4 + 1];
                const float gg = acc[mf][kl * 4 + 2][r] + bb[kl * 4 + 2];
                const float go = acc[mf][kl * 4 + 3][r] + bb[kl * 4 + 3];
                const int k = (2 * wn + kl) * 16 + l15;
                const size_t idx = (size_t)row * 128 + k;
                const float cn = sigmoidf(gf) * c[idx] + sigmoidf(gi) * tanhf(gg);
                const float hn = sigmoidf(go) * tanhf(cn);
                c[idx] = cn;
                hout[idx] = hn;
                ushort hh, hl;
                split1(hn, hh, hl);
                Houth[idx] = hh;
                Houtl[idx] = hl;
            }
        }
}

// ---------------- launch ----------------
extern "C" void kernel_launch(void* const* d_in, const int* in_sizes, int n_in,
                              void* d_out, int out_size, void* d_ws, size_t ws_size,
                              hipStream_t stream) {
    const float* nf  = (const float*)d_in[0];  // [T,N,F]
    const int*   ei  = (const int*)d_in[1];    // [T,2,E]
    const float* W1  = (const float*)d_in[2];
    const float* b1  = (const float*)d_in[3];
    const float* W2  = (const float*)d_in[4];
    const float* b2  = (const float*)d_in[5];
    const float* Wih = (const float*)d_in[6];  // [512,128]
    const float* Whh = (const float*)d_in[7];
    const float* bih = (const float*)d_in[8];
    const float* bhh = (const float*)d_in[9];
    float* h = (float*)d_out;  // [N,128] fp32 hidden (final answer)

    const size_t AL = 256;
    auto rnd = [&](size_t b) { return (b + AL - 1) & ~(AL - 1); };
    const size_t sz_feat  = (size_t)NN * 128 * 4;   // fp32 plane
    const size_t sz_plane = (size_t)NN * 128 * 2;   // bf16 plane
    const size_t need = rnd(sz_feat) * 2                  // hs, c
                      + rnd(sz_plane) * 6                 // xh,xl + 2x h ping-pong hi/lo
                      + rnd((size_t)TT * EE * 4)          // sorted
                      + rnd((size_t)TT * NN * 4) * 3      // dinv, counts, cursor
                      + rnd((size_t)TT * (NN + 1) * 4)    // offs
                      + rnd((size_t)128 * 128 * 2) * 4
                      + rnd((size_t)512 * 128 * 2) * 4
                      + rnd(512 * 4);
    if (ws_size < need) return;  // fail visibly (incorrect), not fatally

    char* ws = (char*)d_ws;
    size_t off = 0;
    auto alloc = [&](size_t bytes) -> void* {
        void* p = ws + off;
        off += rnd(bytes);
        return p;
    };
    float*  hs     = (float*)alloc(sz_feat);
    float*  c      = (float*)alloc(sz_feat);
    ushort* xh     = (ushort*)alloc(sz_plane);
    ushort* xl     = (ushort*)alloc(sz_plane);
    ushort* hp0h   = (ushort*)alloc(sz_plane);
    ushort* hp0l   = (ushort*)alloc(sz_plane);
    ushort* hp1h   = (ushort*)alloc(sz_plane);
    ushort* hp1l   = (ushort*)alloc(sz_plane);
    int*    sorted = (int*)alloc((size_t)TT * EE * 4);
    float*  dinv   = (float*)alloc((size_t)TT * NN * 4);
    int*    counts = (int*)alloc((size_t)TT * NN * 4);
    int*    cursor = (int*)alloc((size_t)TT * NN * 4);
    int*    offs   = (int*)alloc((size_t)TT * (NN + 1) * 4);
    ushort* wf1h   = (ushort*)alloc((size_t)128 * 128 * 2);
    ushort* wf1l   = (ushort*)alloc((size_t)128 * 128 * 2);
    ushort* wf2h   = (ushort*)alloc((size_t)128 * 128 * 2);
    ushort* wf2l   = (ushort*)alloc((size_t)128 * 128 * 2);
    ushort* wihfh  = (ushort*)alloc((size_t)512 * 128 * 2);
    ushort* wihfl  = (ushort*)alloc((size_t)512 * 128 * 2);
    ushort* whhfh  = (ushort*)alloc((size_t)512 * 128 * 2);
    ushort* whhfl  = (ushort*)alloc((size_t)512 * 128 * 2);
    float*  bcp    = (float*)alloc(512 * 4);

    // init
    hipMemsetAsync(c, 0, sz_feat, stream);
    hipMemsetAsync(hp0h, 0, sz_plane, stream);  // bf16 +0.0 == 0x0000
    hipMemsetAsync(hp0l, 0, sz_plane, stream);
    hipMemsetAsync(counts, 0, (size_t)TT * NN * 4, stream);

    // batched CSR build for all 8 timesteps
    count_all<<<dim3(512, TT), 256, 0, stream>>>(ei, counts);
    scan_all<<<TT, 256, 0, stream>>>(counts, offs);
    init_aux<<<(TT * NN + 255) / 256, 256, 0, stream>>>(counts, offs, dinv, cursor);
    fill_all<<<dim3(512, TT), 256, 0, stream>>>(ei, cursor, sorted);

    // weight prep
    prep_w_gcn<<<32, 64, 0, stream>>>(W1, wf1h, wf1l);
    prep_w_gcn<<<32, 64, 0, stream>>>(W2, wf2h, wf2l);
    prep_w_lstm<<<128, 64, 0, stream>>>(Wih, wihfh, wihfl);
    prep_w_lstm<<<128, 64, 0, stream>>>(Whh, whhfh, whhfl);
    prep_bc<<<1, 512, 0, stream>>>(bih, bhh, bcp);

    const int gm64 = (NN + 63) / 64;  // 782

    for (int t = 0; t < TT; ++t) {
        const float* x = nf + (size_t)t * NN * FF;
        const float* dv = dinv + (size_t)t * NN;
        const int* of = offs + (size_t)t * (NN + 1);
        const int* so = sorted + (size_t)t * EE;

        // GCN layer 1 (fp32 A, LDS split)
        gemm_gcn_mfma<<<gm64, 256, 0, stream>>>(x, wf1h, wf1l, dv, hs, NN);
        aggregate_f4<<<(NN * 64) / 256, 256, 0, stream>>>(hs, of, so, dv, b1, xh, xl, NN);
        // GCN layer 2 (bf16 planes A, no LDS)
        gemm_frag<<<gm64, 256, 0, stream>>>(xh, xl, wf2h, wf2l, dv, hs, NN);
        aggregate_f4<<<(NN * 64) / 256, 256, 0, stream>>>(hs, of, so, dv, b2, xh, xl, NN);

        // fused LSTM step (h planes ping-pong)
        const ushort* hinh = (t & 1) ? hp1h : hp0h;
        const ushort* hinl = (t & 1) ? hp1l : hp0l;
        ushort* houth = (t & 1) ? hp0h : hp1h;
        ushort* houtl = (t & 1) ? hp0l : hp1l;
        lstm_frag<<<gm64, 512, 0, stream>>>(xh, xl, hinh, hinl, houth, houtl, h, c,
                                            wihfh, wihfl, whhfh, whhfl, bcp, NN);
    }
}